// Round 5
// baseline (1854.410 us; speedup 1.0000x reference)
//
#include <hip/hip_runtime.h>
#include <hip/hip_fp16.h>
#include <stdint.h>

// ---------------------------------------------------------------------------
// SeqAE: enc LSTM (3->200, T=800, B=256) -> maxpool(T) -> dec LSTM (200->3)
// R5: 1 WG/batch, 1024 threads (16 waves, 4/SIMD, the 128-VGPR occupancy
// point the RA actually grants -- R1/R3/R4 all refused >128 and spilled).
// Full Whh residency: 1024 thr x 100 f16-pair VGPRs = 320KB. Wave-group =
// K-quarter (wave-uniform -> readlane h-broadcast, no LDS pipe pressure);
// lane = unit. Quarters 1-3 ship float4 partials via LDS; quarter-0 waves
// combine + gates + c/h/maxpool. Wih/bias step-invariants read from LDS by
// combiners (keeps register pressure flat). 2 barriers/step.
// ---------------------------------------------------------------------------

typedef _Float16 half2_t __attribute__((ext_vector_type(2)));

__device__ __forceinline__ float fdot2f(uint32_t hp, uint32_t wp, float acc) {
#if __has_builtin(__builtin_amdgcn_fdot2)
  return __builtin_amdgcn_fdot2(__builtin_bit_cast(half2_t, hp),
                                __builtin_bit_cast(half2_t, wp), acc, false);
#else
  half2_t a = __builtin_bit_cast(half2_t, hp);
  half2_t b = __builtin_bit_cast(half2_t, wp);
  return acc + (float)a[0] * (float)b[0] + (float)a[1] * (float)b[1];
#endif
}

__device__ __forceinline__ float hsig(float z) {
  return fminf(fmaxf(__builtin_fmaf(0.2f, z, 0.5f), 0.f), 1.f);
}

__device__ __forceinline__ float tanh_fast(float v) {
  float e = __builtin_amdgcn_exp2f(v * 2.885390081777927f);
  return 1.f - 2.f * __builtin_amdgcn_rcpf(e + 1.f);
}

// --- pack Whh (800x200 f32, row-major) into f16 pairs, layout wpk[pair][row]
__global__ void prep_kernel(const float* __restrict__ whh,
                            uint32_t* __restrict__ wpk) {
  int idx = blockIdx.x * 256 + threadIdx.x;      // 100 pairs * 800 rows
  if (idx >= 80000) return;
  int p = idx / 800;
  int j = idx - p * 800;
  float a = whh[j * 200 + 2 * p];
  float b = whh[j * 200 + 2 * p + 1];
  __half2 v = __floats2half2_rn(a, b);
  wpk[idx] = __builtin_bit_cast(uint32_t, v);
}

// --- fused encoder + maxpool + decoder: grid 256 (batch), 1024 threads
__global__ __launch_bounds__(1024, 4)
void enc_kernel(const float* __restrict__ x,       // (256,3,800)
                const float* __restrict__ wih,     // (800,3)
                const float* __restrict__ bih,     // (800)
                const float* __restrict__ bhh,     // (800)
                const uint32_t* __restrict__ wpk,  // (100,800) f16 pairs
                const float* __restrict__ dwih,    // (12,200)
                const float* __restrict__ dbih,    // (12)
                const float* __restrict__ dbhh,    // (12)
                const float* __restrict__ dwhh,    // (12,3)
                float* __restrict__ out)           // (256,3,800)
{
  const int b = blockIdx.x;
  const int t = threadIdx.x;
  const int lane = t & 63;
  const int wid = t >> 6;            // 0..15
  const int q2 = wid >> 2;           // K-quarter 0..3 (wave-uniform)
  const int u = (wid & 3) * 64 + lane;  // unit 0..255 (200..255 dummy)

  // h quarters at 128B stride so each wave's 25-pair read is one b128
  __shared__ uint32_t hbuf[2][128];            // 2 x 512B, f16 pairs
  __shared__ uint2 xs2[800];                   // (pk(x0,x1), pk(x2,0))
  __shared__ float4 part[3][256];              // quarter 1..3 partials
  __shared__ uint4 wiA[256];                   // gates i,f: {w01,w2_} packs
  __shared__ uint4 wiB[256];                   // gates g,o
  __shared__ float4 biasL[256];
  __shared__ float hist[3200];                 // decoder history [800][4]
  __shared__ float pooled[200];
  __shared__ float pre12s[12];
  __shared__ int s_tc;

  // ---- staging ----
  {
    const float* xb = x + (size_t)b * 2400;
    if (t < 800) {
      __half2 p01 = __floats2half2_rn(xb[t], xb[800 + t]);
      __half2 p23 = __floats2half2_rn(xb[1600 + t], 0.f);
      uint2 v;
      v.x = __builtin_bit_cast(uint32_t, p01);
      v.y = __builtin_bit_cast(uint32_t, p23);
      xs2[t] = v;
    }
    if (t < 256) ((uint32_t*)hbuf)[t] = 0;     // zero both h buffers
    if (t < 256) {
      int uu = t;
      uint4 A, B; float4 bs;
      int r0 = uu < 200 ? uu : 199;
#pragma unroll
      for (int g = 0; g < 4; ++g) {
        int row = r0 + 200 * g;
        __half2 w01 = __floats2half2_rn(wih[row * 3 + 0], wih[row * 3 + 1]);
        __half2 w2_ = __floats2half2_rn(wih[row * 3 + 2], 0.f);
        uint32_t a0 = __builtin_bit_cast(uint32_t, w01);
        uint32_t a1 = __builtin_bit_cast(uint32_t, w2_);
        if (g == 0) { A.x = a0; A.y = a1; }
        else if (g == 1) { A.z = a0; A.w = a1; }
        else if (g == 2) { B.x = a0; B.y = a1; }
        else { B.z = a0; B.w = a1; }
        ((float*)&bs)[g] = bih[row] + bhh[row];
      }
      wiA[uu] = A; wiB[uu] = B; biasL[uu] = bs;
    }
  }

  // ---- resident weights: 4 gate rows x 25 pairs (this wave's K-quarter) ----
  uint32_t w[100];
#pragma unroll
  for (int g = 0; g < 4; ++g) {
    int row = u + 200 * g; if (row > 799) row = 799;   // dummy-unit-safe
    const uint32_t* src = wpk + (size_t)(q2 * 25) * 800 + row;
#pragma unroll
    for (int p = 0; p < 25; ++p) w[g * 25 + p] = src[p * 800];  // coalesced
  }

  float c_state = 0.f;
  float maxh = -INFINITY;

  // precomputed h read/write addresses
  const int pu = u >> 1;
  const int hoff = (pu / 25) * 128 + (pu % 25) * 4 + (u & 1) * 2;
  __half* hW0 = (__half*)((char*)&hbuf[0][0] + hoff);
  __half* hW1 = (__half*)((char*)&hbuf[1][0] + hoff);
  const uint4* h4a = (const uint4*)&hbuf[0][q2 * 32];
  const uint4* h4b = (const uint4*)&hbuf[1][q2 * 32];
  const int lidx = (lane < 7) ? lane : 6;    // lanes 7..63 broadcast chunk 6

  __syncthreads();

  auto STEP = [&](const uint4* srcH, __half* dstH, int step) {
    uint4 hv = srcH[lidx];                    // one b128: 25 pairs + pad
    float a0 = 0.f, a1 = 0.f, a2 = 0.f, a3 = 0.f;
#pragma unroll
    for (int p = 0; p < 25; ++p) {
      const int ln = p >> 2, d = p & 3;
      uint32_t comp = (d == 0) ? hv.x : (d == 1) ? hv.y : (d == 2) ? hv.z : hv.w;
      uint32_t hp = __builtin_amdgcn_readlane(comp, ln);   // SGPR broadcast
      a0 = fdot2f(hp, w[p], a0);
      a1 = fdot2f(hp, w[25 + p], a1);
      a2 = fdot2f(hp, w[50 + p], a2);
      a3 = fdot2f(hp, w[75 + p], a3);
    }
    if (q2 != 0) {
      float4 pv; pv.x = a0; pv.y = a1; pv.z = a2; pv.w = a3;
      part[q2 - 1][u] = pv;
    }
    __syncthreads();
    if (q2 == 0 && u < 200) {
      float4 pa = part[0][u], pb = part[1][u], pc = part[2][u];
      uint4 A = wiA[u], B = wiB[u];
      float4 bs = biasL[u];
      uint2 xv = xs2[step];
      float gi = fdot2f(xv.y, A.y, fdot2f(xv.x, A.x, a0 + pa.x + pb.x + pc.x + bs.x));
      float gf = fdot2f(xv.y, A.w, fdot2f(xv.x, A.z, a1 + pa.y + pb.y + pc.y + bs.y));
      float gg = fdot2f(xv.y, B.y, fdot2f(xv.x, B.x, a2 + pa.z + pb.z + pc.z + bs.z));
      float go = fdot2f(xv.y, B.w, fdot2f(xv.x, B.z, a3 + pa.w + pb.w + pc.w + bs.w));
      float i_ = hsig(gi), f_ = hsig(gf), o_ = hsig(go);
      float g_ = tanh_fast(gg);
      c_state = __builtin_fmaf(f_, c_state, i_ * g_);
      float h_ = o_ * tanh_fast(c_state);
      maxh = fmaxf(maxh, h_);
      *dstH = __float2half(h_);
    }
    __syncthreads();
  };

  for (int sp = 0; sp < 400; ++sp) {
    STEP(h4a, hW1, 2 * sp);
    STEP(h4b, hW0, 2 * sp + 1);
  }

  // ---- maxpool -> decoder constant input pre12 ----
  if (t < 200) pooled[t] = maxh;     // t<200 => wave 0..3, u==t (combiners)
  __syncthreads();
  if (t < 12) {
    float s = dbih[t] + dbhh[t];
    const float* wr = dwih + t * 200;
#pragma unroll 8
    for (int uu = 0; uu < 200; ++uu) s = __builtin_fmaf(pooled[uu], wr[uu], s);
    pre12s[t] = s;
  }
  __syncthreads();

  // ---- decoder: lanes 0..2, 6-dim recurrence, bitwise fixed-point exit ----
  if (t < 3) {
    float pre[12];
#pragma unroll
    for (int j = 0; j < 12; ++j) pre[j] = pre12s[j];
    float W[36];
#pragma unroll
    for (int j = 0; j < 36; ++j) W[j] = dwhh[j];

    float h0 = 0, h1 = 0, h2 = 0, c0 = 0, c1 = 0, c2 = 0;
    int tc = 800;
    for (int step = 0; step < 800; ++step) {
      float g[12];
#pragma unroll
      for (int j = 0; j < 12; ++j) {
        float v = pre[j];
        v = __builtin_fmaf(W[j * 3 + 0], h0, v);
        v = __builtin_fmaf(W[j * 3 + 1], h1, v);
        v = __builtin_fmaf(W[j * 3 + 2], h2, v);
        g[j] = v;
      }
      float nc0 = hsig(g[3]) * c0 + hsig(g[0]) * tanh_fast(g[6]);
      float nc1 = hsig(g[4]) * c1 + hsig(g[1]) * tanh_fast(g[7]);
      float nc2 = hsig(g[5]) * c2 + hsig(g[2]) * tanh_fast(g[8]);
      float nh0 = hsig(g[9])  * tanh_fast(nc0);
      float nh1 = hsig(g[10]) * tanh_fast(nc1);
      float nh2 = hsig(g[11]) * tanh_fast(nc2);
      bool same = (nh0 == h0) && (nh1 == h1) && (nh2 == h2) &&
                  (nc0 == c0) && (nc1 == c1) && (nc2 == c2);
      float mine = (t == 0) ? nh0 : ((t == 1) ? nh1 : nh2);
      hist[step * 4 + t] = mine;
      h0 = nh0; h1 = nh1; h2 = nh2; c0 = nc0; c1 = nc1; c2 = nc2;
      if (same) { tc = step + 1; break; }       // exact fixed point
    }
    if (t == 0) s_tc = tc;
  }
  __syncthreads();

  // ---- coalesced writeback: out[b, f, tt] = hist[f][min(tt, tc-1)] ----
  {
    const int tcv = s_tc, tc1 = tcv - 1;
    float* ob = out + (size_t)b * 2400;
    if (t < 800) {
      int idx = (t < tcv) ? t : tc1;
      ob[t]        = hist[idx * 4 + 0];
      ob[800 + t]  = hist[idx * 4 + 1];
      ob[1600 + t] = hist[idx * 4 + 2];
    }
  }
}

extern "C" void kernel_launch(void* const* d_in, const int* in_sizes, int n_in,
                              void* d_out, int out_size, void* d_ws, size_t ws_size,
                              hipStream_t stream)
{
  const float* x    = (const float*)d_in[0];
  const float* wih  = (const float*)d_in[1];
  const float* whh  = (const float*)d_in[2];
  const float* bih  = (const float*)d_in[3];
  const float* bhh  = (const float*)d_in[4];
  const float* dwih = (const float*)d_in[5];
  const float* dwhh = (const float*)d_in[6];
  const float* dbih = (const float*)d_in[7];
  const float* dbhh = (const float*)d_in[8];
  float* out = (float*)d_out;

  uint32_t* wpk = (uint32_t*)d_ws;   // 320000 B

  hipLaunchKernelGGL(prep_kernel, dim3(313), dim3(256), 0, stream, whh, wpk);
  hipLaunchKernelGGL(enc_kernel, dim3(256), dim3(1024), 0, stream,
                     x, wih, bih, bhh, wpk, dwih, dbih, dbhh, dwhh, out);
}

// Round 6
// 1296.633 us; speedup vs baseline: 1.4302x; 1.4302x over previous
//
#include <hip/hip_runtime.h>
#include <hip/hip_fp16.h>
#include <stdint.h>

// ---------------------------------------------------------------------------
// SeqAE: enc LSTM (3->200, T=800, B=256) -> maxpool(T) -> dec LSTM (200->3)
// R6: 1 WG/batch, 1024 threads (16 waves, 4/SIMD, VGPR cap 128). Wave-group =
// K-quarter, lane = unit; thread holds 100 f16-pair weight VGPRs (full Whh
// residency: 1024 x 100 dw = 320KB). Straight-line step body (R5's lambda put
// w[] in scratch: VGPR=64, WRITE 164MB) + opaque asm pins (block remat-sink;
// R1 reloaded from L2 at ~56B/cy/CU = the measured 2900cy/step). Pressure
// designed to ~120 <= 128: bias folded into quarter-1 acc init, Wih*x done by
// quarter-2 (ext[8]), combiners only add partials + nonlinearity.
// ---------------------------------------------------------------------------

typedef _Float16 half2_t __attribute__((ext_vector_type(2)));

__device__ __forceinline__ float fdot2f(uint32_t hp, uint32_t wp, float acc) {
#if __has_builtin(__builtin_amdgcn_fdot2)
  return __builtin_amdgcn_fdot2(__builtin_bit_cast(half2_t, hp),
                                __builtin_bit_cast(half2_t, wp), acc, false);
#else
  half2_t a = __builtin_bit_cast(half2_t, hp);
  half2_t b = __builtin_bit_cast(half2_t, wp);
  return acc + (float)a[0] * (float)b[0] + (float)a[1] * (float)b[1];
#endif
}

__device__ __forceinline__ float hsig(float z) {
  return fminf(fmaxf(__builtin_fmaf(0.2f, z, 0.5f), 0.f), 1.f);
}

__device__ __forceinline__ float tanh_fast(float v) {
  float e = __builtin_amdgcn_exp2f(v * 2.885390081777927f);
  return 1.f - 2.f * __builtin_amdgcn_rcpf(e + 1.f);
}

// --- pack Whh (800x200 f32, row-major) into f16 pairs, layout wpk[pair][row]
__global__ void prep_kernel(const float* __restrict__ whh,
                            uint32_t* __restrict__ wpk) {
  int idx = blockIdx.x * 256 + threadIdx.x;      // 100 pairs * 800 rows
  if (idx >= 80000) return;
  int p = idx / 800;
  int j = idx - p * 800;
  float a = whh[j * 200 + 2 * p];
  float b = whh[j * 200 + 2 * p + 1];
  __half2 v = __floats2half2_rn(a, b);
  wpk[idx] = __builtin_bit_cast(uint32_t, v);
}

// --- fused encoder + maxpool + decoder: grid 256 (batch), 1024 threads
__global__ __launch_bounds__(1024, 4)
void enc_kernel(const float* __restrict__ x,       // (256,3,800)
                const float* __restrict__ wih,     // (800,3)
                const float* __restrict__ bih,     // (800)
                const float* __restrict__ bhh,     // (800)
                const uint32_t* __restrict__ wpk,  // (100,800) f16 pairs
                const float* __restrict__ dwih,    // (12,200)
                const float* __restrict__ dbih,    // (12)
                const float* __restrict__ dbhh,    // (12)
                const float* __restrict__ dwhh,    // (12,3)
                float* __restrict__ out)           // (256,3,800)
{
  const int b = blockIdx.x;
  const int t = threadIdx.x;
  const int lane = t & 63;
  const int wid = t >> 6;               // 0..15
  const int q2 = wid >> 2;              // K-quarter 0..3 (wave-uniform)
  const int u = (wid & 3) * 64 + lane;  // unit 0..255 (200..255 dummy)

  __shared__ uint32_t hbuf[2][128];     // h quarters @128B stride, f16 pairs
  __shared__ uint2 xs2[800];            // (pk(x0,x1), pk(x2,0))
  __shared__ float4 part[3][256];       // quarter 1..3 partials
  __shared__ float hist[3200];          // decoder history [800][4]
  __shared__ float pooled[200];
  __shared__ float pre12s[12];
  __shared__ int s_tc;

  // ---- staging ----
  {
    const float* xb = x + (size_t)b * 2400;
    if (t < 800) {
      __half2 p01 = __floats2half2_rn(xb[t], xb[800 + t]);
      __half2 p23 = __floats2half2_rn(xb[1600 + t], 0.f);
      uint2 v;
      v.x = __builtin_bit_cast(uint32_t, p01);
      v.y = __builtin_bit_cast(uint32_t, p23);
      xs2[t] = v;
    }
    if (t < 256) ((uint32_t*)hbuf)[t] = 0;   // zero both h buffers
  }

  // ---- resident weights: 4 gate rows x 25 pairs (this wave's K-quarter) ----
  uint32_t w[100];
#pragma unroll
  for (int g = 0; g < 4; ++g) {
    int row = u + 200 * g; if (row > 799) row = 799;   // dummy-unit-safe
    const uint32_t* src = wpk + (size_t)(q2 * 25) * 800 + row;
#pragma unroll
    for (int p = 0; p < 25; ++p) w[g * 25 + p] = src[p * 800];  // coalesced
  }
#pragma unroll
  for (int i = 0; i < 100; ++i) asm volatile("" : "+v"(w[i]));  // block remat

  // ---- per-quarter step-invariants (keeps combiner pressure flat) ----
  // q2==1: ext[0..3] = bias (folded into acc init)
  // q2==2: ext[0..7] = packed f16 Wih pairs {w01, w2_} per gate
  uint32_t ext[8];
#pragma unroll
  for (int j = 0; j < 8; ++j) ext[j] = 0;
  if (q2 == 1) {
#pragma unroll
    for (int g = 0; g < 4; ++g) {
      int row = u + 200 * g; if (row > 799) row = 799;
      ext[g] = __builtin_bit_cast(uint32_t, bih[row] + bhh[row]);
    }
  } else if (q2 == 2) {
#pragma unroll
    for (int g = 0; g < 4; ++g) {
      int row = u + 200 * g; if (row > 799) row = 799;
      __half2 w01 = __floats2half2_rn(wih[row * 3 + 0], wih[row * 3 + 1]);
      __half2 w2_ = __floats2half2_rn(wih[row * 3 + 2], 0.f);
      ext[2 * g]     = __builtin_bit_cast(uint32_t, w01);
      ext[2 * g + 1] = __builtin_bit_cast(uint32_t, w2_);
    }
  }
#pragma unroll
  for (int j = 0; j < 8; ++j) asm volatile("" : "+v"(ext[j]));

  float c_state = 0.f;
  float maxh = -INFINITY;

  // h addresses: read one b128 covering this quarter's 25 pairs (+3 pad)
  const int lidx = (lane < 7) ? lane : 6;
  const int pu = u >> 1;
  const int hoff = (pu / 25) * 128 + (pu % 25) * 4 + (u & 1) * 2;  // bytes
  __half* hW0 = (__half*)((char*)&hbuf[0][0] + hoff);
  __half* hW1 = (__half*)((char*)&hbuf[1][0] + hoff);

  __syncthreads();

#define ENC_STEP(SRCBUF, DSTPTR, STEPIDX)                                    \
  {                                                                          \
    uint4 hv = ((const uint4*)&hbuf[SRCBUF][q2 * 32])[lidx];                 \
    float a0, a1, a2, a3;                                                    \
    if (q2 == 1) {                                                           \
      a0 = __builtin_bit_cast(float, ext[0]);                                \
      a1 = __builtin_bit_cast(float, ext[1]);                                \
      a2 = __builtin_bit_cast(float, ext[2]);                                \
      a3 = __builtin_bit_cast(float, ext[3]);                                \
    } else { a0 = a1 = a2 = a3 = 0.f; }                                      \
    _Pragma("unroll")                                                        \
    for (int p = 0; p < 25; ++p) {                                           \
      const int ln = p >> 2, d = p & 3;                                      \
      uint32_t comp = (d == 0) ? hv.x : (d == 1) ? hv.y                      \
                    : (d == 2) ? hv.z : hv.w;                                \
      uint32_t hp = __builtin_amdgcn_readlane(comp, ln);                     \
      a0 = fdot2f(hp, w[p], a0);                                             \
      a1 = fdot2f(hp, w[25 + p], a1);                                        \
      a2 = fdot2f(hp, w[50 + p], a2);                                        \
      a3 = fdot2f(hp, w[75 + p], a3);                                        \
    }                                                                        \
    if (q2 == 2) {                                                           \
      uint2 xv = xs2[STEPIDX];          /* broadcast b64 */                  \
      a0 = fdot2f(xv.y, ext[1], fdot2f(xv.x, ext[0], a0));                   \
      a1 = fdot2f(xv.y, ext[3], fdot2f(xv.x, ext[2], a1));                   \
      a2 = fdot2f(xv.y, ext[5], fdot2f(xv.x, ext[4], a2));                   \
      a3 = fdot2f(xv.y, ext[7], fdot2f(xv.x, ext[6], a3));                   \
    }                                                                        \
    if (q2 != 0) {                                                           \
      float4 pv; pv.x = a0; pv.y = a1; pv.z = a2; pv.w = a3;                 \
      part[q2 - 1][u] = pv;                                                  \
    }                                                                        \
    __syncthreads();                                                         \
    if (q2 == 0 && u < 200) {                                                \
      float4 pa = part[0][u]; a0 += pa.x; a1 += pa.y; a2 += pa.z; a3 += pa.w;\
      float4 pb = part[1][u]; a0 += pb.x; a1 += pb.y; a2 += pb.z; a3 += pb.w;\
      float4 pc = part[2][u]; a0 += pc.x; a1 += pc.y; a2 += pc.z; a3 += pc.w;\
      float i_ = hsig(a0), f_ = hsig(a1), o_ = hsig(a3);                     \
      float g_ = tanh_fast(a2);                                              \
      c_state = __builtin_fmaf(f_, c_state, i_ * g_);                        \
      float h_ = o_ * tanh_fast(c_state);                                    \
      maxh = fmaxf(maxh, h_);                                                \
      *(DSTPTR) = __float2half(h_);                                          \
    }                                                                        \
    __syncthreads();                                                         \
  }

  for (int sp = 0; sp < 400; ++sp) {
    ENC_STEP(0, hW1, 2 * sp)
    ENC_STEP(1, hW0, 2 * sp + 1)
  }
#undef ENC_STEP

  // ---- maxpool -> decoder constant input pre12 ----
  if (q2 == 0 && u < 200) pooled[u] = maxh;   // == threads t<200
  __syncthreads();
  if (t < 12) {
    float s = dbih[t] + dbhh[t];
    const float* wr = dwih + t * 200;
#pragma unroll 8
    for (int uu = 0; uu < 200; ++uu) s = __builtin_fmaf(pooled[uu], wr[uu], s);
    pre12s[t] = s;
  }
  __syncthreads();

  // ---- decoder: lanes 0..2, 6-dim recurrence, bitwise fixed-point exit ----
  if (t < 3) {
    float pre[12];
#pragma unroll
    for (int j = 0; j < 12; ++j) pre[j] = pre12s[j];
    float W[36];
#pragma unroll
    for (int j = 0; j < 36; ++j) W[j] = dwhh[j];

    float h0 = 0, h1 = 0, h2 = 0, c0 = 0, c1 = 0, c2 = 0;
    int tc = 800;
    for (int step = 0; step < 800; ++step) {
      float g[12];
#pragma unroll
      for (int j = 0; j < 12; ++j) {
        float v = pre[j];
        v = __builtin_fmaf(W[j * 3 + 0], h0, v);
        v = __builtin_fmaf(W[j * 3 + 1], h1, v);
        v = __builtin_fmaf(W[j * 3 + 2], h2, v);
        g[j] = v;
      }
      float nc0 = hsig(g[3]) * c0 + hsig(g[0]) * tanh_fast(g[6]);
      float nc1 = hsig(g[4]) * c1 + hsig(g[1]) * tanh_fast(g[7]);
      float nc2 = hsig(g[5]) * c2 + hsig(g[2]) * tanh_fast(g[8]);
      float nh0 = hsig(g[9])  * tanh_fast(nc0);
      float nh1 = hsig(g[10]) * tanh_fast(nc1);
      float nh2 = hsig(g[11]) * tanh_fast(nc2);
      bool same = (nh0 == h0) && (nh1 == h1) && (nh2 == h2) &&
                  (nc0 == c0) && (nc1 == c1) && (nc2 == c2);
      float mine = (t == 0) ? nh0 : ((t == 1) ? nh1 : nh2);
      hist[step * 4 + t] = mine;
      h0 = nh0; h1 = nh1; h2 = nh2; c0 = nc0; c1 = nc1; c2 = nc2;
      if (same) { tc = step + 1; break; }       // exact fixed point
    }
    if (t == 0) s_tc = tc;
  }
  __syncthreads();

  // ---- coalesced writeback: out[b, f, tt] = hist[f][min(tt, tc-1)] ----
  {
    const int tcv = s_tc, tc1 = tcv - 1;
    float* ob = out + (size_t)b * 2400;
    if (t < 800) {
      int idx = (t < tcv) ? t : tc1;
      ob[t]        = hist[idx * 4 + 0];
      ob[800 + t]  = hist[idx * 4 + 1];
      ob[1600 + t] = hist[idx * 4 + 2];
    }
  }
}

extern "C" void kernel_launch(void* const* d_in, const int* in_sizes, int n_in,
                              void* d_out, int out_size, void* d_ws, size_t ws_size,
                              hipStream_t stream)
{
  const float* x    = (const float*)d_in[0];
  const float* wih  = (const float*)d_in[1];
  const float* whh  = (const float*)d_in[2];
  const float* bih  = (const float*)d_in[3];
  const float* bhh  = (const float*)d_in[4];
  const float* dwih = (const float*)d_in[5];
  const float* dwhh = (const float*)d_in[6];
  const float* dbih = (const float*)d_in[7];
  const float* dbhh = (const float*)d_in[8];
  float* out = (float*)d_out;

  uint32_t* wpk = (uint32_t*)d_ws;   // 320000 B

  hipLaunchKernelGGL(prep_kernel, dim3(313), dim3(256), 0, stream, whh, wpk);
  hipLaunchKernelGGL(enc_kernel, dim3(256), dim3(1024), 0, stream,
                     x, wih, bih, bhh, wpk, dwih, dbih, dbhh, dwhh, out);
}